// Round 8
// baseline (589.626 us; speedup 1.0000x reference)
//
#include <hip/hip_runtime.h>
#include <hip/hip_bf16.h>

// GraphNet: N=50000 nodes, F=128 feats, H=128, MH=256, E=800000 edges
// Inputs FP32; bf16 workspace copies for MFMA; fp32 MFMA accumulation.
// Edge MLP decomposed: P[n]=h2[n]@W1s^T, Q[n]=h2[n]@W1d^T+bm1 (node-level GEMM),
// then out[e] = relu(P[src]+Q[dst]).Wm2 + bm2 (per-edge dot, 32x less FLOPs).
#define NN 50000
#define F 128
#define EE 800000
#define MHD 256

typedef __attribute__((ext_vector_type(8))) short bf16x8;
typedef __attribute__((ext_vector_type(4))) float f32x4;

__device__ __forceinline__ float b2f(unsigned short u) {
    union { unsigned int i; float f; } v; v.i = ((unsigned)u) << 16; return v.f;
}
__device__ __forceinline__ unsigned short f2b(float f) {
    unsigned int x = __float_as_uint(f);
    unsigned int r = x + 0x7fffu + ((x >> 16) & 1u);   // RNE
    return (unsigned short)(r >> 16);
}

// ---------------- fp32 -> bf16 cast of x ----------------
__global__ __launch_bounds__(256) void cast_x_kernel(
    const float* __restrict__ in, unsigned short* __restrict__ out) {
    int i = (blockIdx.x * 256 + threadIdx.x) * 4;
    float4 v = *(const float4*)(in + i);
    ushort4 o; o.x = f2b(v.x); o.y = f2b(v.y); o.z = f2b(v.z); o.w = f2b(v.w);
    *(ushort4*)(out + i) = o;
}

// ---------------- fp32 -> bf16 cast of the 5 weight matrices ----------------
// wb elems: W1l@0, W1r@16384, W2l@32768, W2r@49152, Wm1@65536 (65536 elems, row-major [256,256])
__global__ __launch_bounds__(256) void cast_w_kernel(
    const float* __restrict__ W1l, const float* __restrict__ W1r,
    const float* __restrict__ W2l, const float* __restrict__ W2r,
    const float* __restrict__ Wm1, unsigned short* __restrict__ wb) {
    int i = (blockIdx.x * 256 + threadIdx.x) * 4;        // 131072 elems / 4
    const float* p;
    if (i < 16384)      p = W1l + i;
    else if (i < 32768) p = W1r + (i - 16384);
    else if (i < 49152) p = W2l + (i - 32768);
    else if (i < 65536) p = W2r + (i - 49152);
    else                p = Wm1 + (i - 65536);
    float4 v = *(const float4*)p;
    ushort4 o; o.x = f2b(v.x); o.y = f2b(v.y); o.z = f2b(v.z); o.w = f2b(v.w);
    *(ushort4*)(wb + i) = o;
}

// ---------------- edge_index canonicalize -> int32 src/dst ----------------
__global__ __launch_bounds__(256) void edge_cvt_kernel(
    const int* __restrict__ ei, int* __restrict__ s32, int* __restrict__ d32) {
    __shared__ int isI64;
    if (threadIdx.x == 0) {
        int z = 0;
        for (int i = 1; i < 128; i += 2) z |= ei[i];
        isI64 = (z == 0) ? 1 : 0;
    }
    __syncthreads();
    int e = blockIdx.x * 256 + threadIdx.x;
    if (e >= EE) return;
    if (isI64) {
        const long long* e64 = (const long long*)ei;
        s32[e] = (int)e64[e];
        d32[e] = (int)e64[EE + e];
    } else {
        s32[e] = ei[e];
        d32[e] = ei[EE + e];
    }
}

// ---------------- CSR build: histogram -> scan -> fill (with edge ids) ----------------
__global__ __launch_bounds__(256) void hist_kernel(
    const int* __restrict__ d32, int* __restrict__ deg) {
    int e = blockIdx.x * 256 + threadIdx.x;
    if (e < EE) atomicAdd(&deg[d32[e]], 1);
}

#define SCAN_T 1024
#define SCHUNK 49   // 1024*49 = 50176 >= NN
__global__ __launch_bounds__(1024) void scan_kernel(
    const int* __restrict__ deg, int* __restrict__ rowstart, int* __restrict__ cursor) {
    __shared__ int part[SCAN_T];
    int t = threadIdx.x;
    int beg = t * SCHUNK, end = min(beg + SCHUNK, NN);
    int s = 0;
    for (int i = beg; i < end; i++) s += deg[i];
    part[t] = s;
    __syncthreads();
    for (int off = 1; off < SCAN_T; off <<= 1) {
        int v = (t >= off) ? part[t - off] : 0;
        __syncthreads();
        part[t] += v;
        __syncthreads();
    }
    int run = (t == 0) ? 0 : part[t - 1];
    for (int i = beg; i < end; i++) {
        rowstart[i] = run; cursor[i] = run; run += deg[i];
    }
    if (t == SCAN_T - 1) rowstart[NN] = run;
}

__global__ __launch_bounds__(256) void fill_kernel(
    const int* __restrict__ s32, const int* __restrict__ d32,
    int* __restrict__ cursor, int* __restrict__ nbr, int* __restrict__ eid) {
    int e = blockIdx.x * 256 + threadIdx.x;
    if (e < EE) {
        int p = atomicAdd(&cursor[d32[e]], 1);
        nbr[p] = s32[e];
        eid[p] = e;
    }
}

// ---------------- gather aggregation + mean ----------------
// One wave/node; 16 lanes x 16B per neighbor row -> 4 nbrs/load; 4 loads in flight.
__global__ __launch_bounds__(256) void agg_gather_kernel(
    const unsigned short* __restrict__ xin,
    const int* __restrict__ nbr, const int* __restrict__ rowstart,
    unsigned short* __restrict__ aggb) {
    int wave = threadIdx.x >> 6, lane = threadIdx.x & 63;
    int node = blockIdx.x * 4 + wave;
    if (node >= NN) return;
    int part = lane >> 4;                    // 0..3: which neighbor in group of 4
    int col8 = (lane & 15) * 8;              // 8 feats per lane
    int beg = rowstart[node], end = rowstart[node + 1];
    float a[8] = {0,0,0,0,0,0,0,0};
    float b[8] = {0,0,0,0,0,0,0,0};
    int j = beg + part;
    for (; j + 12 < end; j += 16) {          // 4 outstanding 16B loads, 16 nbrs/wave in flight
        int s0 = nbr[j], s1 = nbr[j + 4], s2 = nbr[j + 8], s3 = nbr[j + 12];
        bf16x8 v0 = *(const bf16x8*)(xin + (size_t)s0 * F + col8);
        bf16x8 v1 = *(const bf16x8*)(xin + (size_t)s1 * F + col8);
        bf16x8 v2 = *(const bf16x8*)(xin + (size_t)s2 * F + col8);
        bf16x8 v3 = *(const bf16x8*)(xin + (size_t)s3 * F + col8);
        for (int i = 0; i < 8; i++) a[i] += b2f((unsigned short)v0[i]);
        for (int i = 0; i < 8; i++) b[i] += b2f((unsigned short)v1[i]);
        for (int i = 0; i < 8; i++) a[i] += b2f((unsigned short)v2[i]);
        for (int i = 0; i < 8; i++) b[i] += b2f((unsigned short)v3[i]);
    }
    for (; j < end; j += 4) {
        int s0 = nbr[j];
        bf16x8 v0 = *(const bf16x8*)(xin + (size_t)s0 * F + col8);
        for (int i = 0; i < 8; i++) a[i] += b2f((unsigned short)v0[i]);
    }
    float inv = 1.0f / fmaxf((float)(end - beg), 1.0f);
    unsigned short o[8];
    for (int i = 0; i < 8; i++) {
        float v = a[i] + b[i];
        v += __shfl_xor(v, 16);
        v += __shfl_xor(v, 32);
        o[i] = f2b(v * inv);
    }
    if (part == 0)
        *(bf16x8*)(aggb + (size_t)node * F + col8) = *(bf16x8*)o;
}

// ---------------- fused SAGE combine: out = relu(A1@W1^T + bias + A2@W2^T) ----------------
__global__ __launch_bounds__(256) void node_gemm_kernel(
    const unsigned short* __restrict__ A1, const unsigned short* __restrict__ A2,
    const unsigned short* __restrict__ W1, const unsigned short* __restrict__ W2,
    const float* __restrict__ bias,
    unsigned short* __restrict__ out) {
    int wave = threadIdx.x >> 6, lane = threadIdx.x & 63;
    int c = lane & 15, q = lane >> 4;
    int m0 = (blockIdx.x * 4 + wave) * 16;
    if (m0 >= NN) return;
    f32x4 acc[8];
    for (int nt = 0; nt < 8; nt++) {
        float b = bias[nt * 16 + c];
        acc[nt] = (f32x4){b, b, b, b};
    }
    int mrow = m0 + c; if (mrow > NN - 1) mrow = NN - 1;
    for (int op = 0; op < 2; op++) {
        const unsigned short* ap = (op ? A2 : A1) + (size_t)mrow * F + q * 8;
        const unsigned short* W  = op ? W2 : W1;
        for (int kb = 0; kb < 4; kb++) {
            bf16x8 a = *(const bf16x8*)(ap + kb * 32);
            for (int nt = 0; nt < 8; nt++) {
                bf16x8 b = *(const bf16x8*)(W + (size_t)(nt * 16 + c) * F + kb * 32 + q * 8);
                acc[nt] = __builtin_amdgcn_mfma_f32_16x16x32_bf16(a, b, acc[nt], 0, 0, 0);
            }
        }
    }
    for (int nt = 0; nt < 8; nt++) {
        for (int r = 0; r < 4; r++) {
            int node = m0 + q * 4 + r;
            if (node < NN) {
                float v = fmaxf(acc[nt][r], 0.0f);
                out[(size_t)node * F + nt * 16 + c] = f2b(v);
            }
        }
    }
}

// ---------------- PQ GEMM: PQ[n] = [h2[n]@W1s^T | h2[n]@W1d^T + bm1], bf16 [N,512] ----------
// W1s = Wm1[:, :128], W1d = Wm1[:, 128:]. 16 nodes/wave, N=512 as 2 halves x 16 n-tiles.
__global__ __launch_bounds__(256) void pq_gemm_kernel(
    const unsigned short* __restrict__ h,      // h2 [N,128] bf16
    const unsigned short* __restrict__ wmb,    // Wm1 bf16 [256,256] row-major
    const float* __restrict__ bm1,             // [256] fp32
    unsigned short* __restrict__ PQ) {         // [N,512] bf16
    int wave = threadIdx.x >> 6, lane = threadIdx.x & 63;
    int c = lane & 15, q = lane >> 4;
    int m0 = (blockIdx.x * 4 + wave) * 16;
    if (m0 >= NN) return;
    int mrow = m0 + c; if (mrow > NN - 1) mrow = NN - 1;
    bf16x8 a[4];
#pragma unroll
    for (int kb = 0; kb < 4; kb++)
        a[kb] = *(const bf16x8*)(h + (size_t)mrow * F + kb * 32 + q * 8);
    for (int half = 0; half < 2; half++) {
        f32x4 acc[16];
#pragma unroll
        for (int nt = 0; nt < 16; nt++) {
            float b = half ? bm1[nt * 16 + c] : 0.0f;
            acc[nt] = (f32x4){b, b, b, b};
        }
#pragma unroll
        for (int kb = 0; kb < 4; kb++) {
#pragma unroll
            for (int nt = 0; nt < 16; nt++) {
                bf16x8 b = *(const bf16x8*)(wmb + (size_t)(nt * 16 + c) * 256 + half * 128 + kb * 32 + q * 8);
                acc[nt] = __builtin_amdgcn_mfma_f32_16x16x32_bf16(a[kb], b, acc[nt], 0, 0, 0);
            }
        }
#pragma unroll
        for (int nt = 0; nt < 16; nt++) {
#pragma unroll
            for (int r = 0; r < 4; r++) {
                int node = m0 + q * 4 + r;
                if (node < NN)
                    PQ[(size_t)node * 512 + half * 256 + nt * 16 + c] = f2b(acc[nt][r]);
            }
        }
    }
}

// ---------------- edge dot: out[eid] = relu(P[src]+Q[dst]).Wm2 + bm2 ----------------
// One wave per dst node via CSR; lane l holds cols l*4..l*4+3; Q loaded once per node.
__global__ __launch_bounds__(256) void edge_dot_kernel(
    const unsigned short* __restrict__ PQ,
    const int* __restrict__ nbr, const int* __restrict__ eid,
    const int* __restrict__ rowstart,
    const float* __restrict__ Wm2, const float* __restrict__ bm2,
    float* __restrict__ out) {
    int wave = threadIdx.x >> 6, lane = threadIdx.x & 63;
    int node = blockIdx.x * 4 + wave;
    if (node >= NN) return;
    float4 w2 = *(const float4*)(Wm2 + lane * 4);
    float b2 = bm2[0];
    ushort4 qv = *(const ushort4*)(PQ + (size_t)node * 512 + 256 + lane * 4);
    float q0 = b2f(qv.x), q1 = b2f(qv.y), q2 = b2f(qv.z), q3 = b2f(qv.w);
    int beg = rowstart[node], end = rowstart[node + 1];
    int j = beg;
    for (; j + 1 < end; j += 2) {
        int s0 = nbr[j], s1 = nbr[j + 1];
        int i0 = eid[j], i1 = eid[j + 1];
        ushort4 p0 = *(const ushort4*)(PQ + (size_t)s0 * 512 + lane * 4);
        ushort4 p1 = *(const ushort4*)(PQ + (size_t)s1 * 512 + lane * 4);
        float t0 = fmaxf(b2f(p0.x) + q0, 0.f) * w2.x + fmaxf(b2f(p0.y) + q1, 0.f) * w2.y
                 + fmaxf(b2f(p0.z) + q2, 0.f) * w2.z + fmaxf(b2f(p0.w) + q3, 0.f) * w2.w;
        float t1 = fmaxf(b2f(p1.x) + q0, 0.f) * w2.x + fmaxf(b2f(p1.y) + q1, 0.f) * w2.y
                 + fmaxf(b2f(p1.z) + q2, 0.f) * w2.z + fmaxf(b2f(p1.w) + q3, 0.f) * w2.w;
#pragma unroll
        for (int o = 1; o < 64; o <<= 1) {
            t0 += __shfl_xor(t0, o);
            t1 += __shfl_xor(t1, o);
        }
        if (lane == 0) { out[i0] = t0 + b2; out[i1] = t1 + b2; }
    }
    if (j < end) {
        int s0 = nbr[j];
        int i0 = eid[j];
        ushort4 p0 = *(const ushort4*)(PQ + (size_t)s0 * 512 + lane * 4);
        float t0 = fmaxf(b2f(p0.x) + q0, 0.f) * w2.x + fmaxf(b2f(p0.y) + q1, 0.f) * w2.y
                 + fmaxf(b2f(p0.z) + q2, 0.f) * w2.z + fmaxf(b2f(p0.w) + q3, 0.f) * w2.w;
#pragma unroll
        for (int o = 1; o < 64; o <<= 1) t0 += __shfl_xor(t0, o);
        if (lane == 0) out[i0] = t0 + b2;
    }
}

extern "C" void kernel_launch(void* const* d_in, const int* in_sizes, int n_in,
                              void* d_out, int out_size, void* d_ws, size_t ws_size,
                              hipStream_t stream) {
    const float* x   = (const float*)d_in[0];
    const int*   ei  = (const int*)d_in[1];
    const float* W1l = (const float*)d_in[2];
    const float* b1l = (const float*)d_in[3];
    const float* W1r = (const float*)d_in[4];
    const float* W2l = (const float*)d_in[5];
    const float* b2l = (const float*)d_in[6];
    const float* W2r = (const float*)d_in[7];
    const float* Wm1 = (const float*)d_in[8];
    const float* bm1 = (const float*)d_in[9];
    const float* Wm2 = (const float*)d_in[10];
    const float* bm2 = (const float*)d_in[11];

    // workspace (bytes), with overlays (lifetimes disjoint):
    //   PQ bf16 [50k,512] @0 (51.2M) OVERLAYS {xb@0, h1@12.8M, aggb@25.6M} (dead before pq_gemm)
    //   wb @51.2M (262K) | s32 @51.462M | d32 @54.662M | deg @57.862M | rowstart @58.062M
    //   cursor @58.262M | nbr @58.462M | eid @61.662M | h2 @64.862M (12.8M)  -> peak 77.7M
    char* ws = (char*)d_ws;
    unsigned short* PQ       = (unsigned short*)(ws);
    unsigned short* xb       = (unsigned short*)(ws);
    unsigned short* h1       = (unsigned short*)(ws + 12800000);
    unsigned short* aggb     = (unsigned short*)(ws + 25600000);
    unsigned short* wb       = (unsigned short*)(ws + 51200000);
    int*            s32      = (int*)(ws + 51462144);
    int*            d32      = (int*)(ws + 54662144);
    int*            deg      = (int*)(ws + 57862144);
    int*            rowstart = (int*)(ws + 58062208);
    int*            cursor   = (int*)(ws + 58262272);
    int*            nbr      = (int*)(ws + 58462336);
    int*            eid      = (int*)(ws + 61662336);
    unsigned short* h2       = (unsigned short*)(ws + 64862336);
    float*          outp     = (float*)d_out;

    const unsigned short* w1l_b = wb;
    const unsigned short* w1r_b = wb + 16384;
    const unsigned short* w2l_b = wb + 32768;
    const unsigned short* w2r_b = wb + 49152;
    const unsigned short* wm1_b = wb + 65536;        // plain bf16 [256,256]

    // prep: casts + indices + CSR build (dst-sorted, with edge ids)
    cast_x_kernel<<<6250, 256, 0, stream>>>(x, xb);
    cast_w_kernel<<<128, 256, 0, stream>>>(W1l, W1r, W2l, W2r, Wm1, wb);
    edge_cvt_kernel<<<3125, 256, 0, stream>>>(ei, s32, d32);
    hipMemsetAsync(deg, 0, 200064, stream);
    hist_kernel<<<3125, 256, 0, stream>>>(d32, deg);
    scan_kernel<<<1, 1024, 0, stream>>>(deg, rowstart, cursor);
    fill_kernel<<<3125, 256, 0, stream>>>(s32, d32, cursor, nbr, eid);

    // layer 1
    agg_gather_kernel<<<12500, 256, 0, stream>>>(xb, nbr, rowstart, aggb);
    node_gemm_kernel<<<782, 256, 0, stream>>>(aggb, xb, w1l_b, w1r_b, b1l, h1);
    // layer 2
    agg_gather_kernel<<<12500, 256, 0, stream>>>(h1, nbr, rowstart, aggb);
    node_gemm_kernel<<<782, 256, 0, stream>>>(aggb, h1, w2l_b, w2r_b, b2l, h2);
    // edge MLP (decomposed)
    pq_gemm_kernel<<<782, 256, 0, stream>>>(h2, wm1_b, bm1, PQ);
    edge_dot_kernel<<<12500, 256, 0, stream>>>(PQ, nbr, eid, rowstart, Wm2, bm2, outp);
}

// Round 9
// 482.724 us; speedup vs baseline: 1.2215x; 1.2215x over previous
//
#include <hip/hip_runtime.h>
#include <hip/hip_bf16.h>

// GraphNet: N=50000 nodes, F=128 feats, H=128, MH=256, E=800000 edges
// Inputs FP32; bf16 workspace copies for MFMA; fp32 MFMA accumulation.
// Edge MLP decomposed: P[n]=h2[n]@W1s^T, Q[n]=h2[n]@W1d^T+bm1 (node-level GEMM),
// then out[e] = relu(P[src]+Q[dst]).Wm2 + bm2 (per-edge dot).
#define NN 50000
#define F 128
#define EE 800000
#define MHD 256

typedef __attribute__((ext_vector_type(8))) short bf16x8;
typedef __attribute__((ext_vector_type(4))) float f32x4;

__device__ __forceinline__ float b2f(unsigned short u) {
    union { unsigned int i; float f; } v; v.i = ((unsigned)u) << 16; return v.f;
}
__device__ __forceinline__ unsigned short f2b(float f) {
    unsigned int x = __float_as_uint(f);
    unsigned int r = x + 0x7fffu + ((x >> 16) & 1u);   // RNE
    return (unsigned short)(r >> 16);
}

// ---------------- fp32 -> bf16 cast of x ----------------
__global__ __launch_bounds__(256) void cast_x_kernel(
    const float* __restrict__ in, unsigned short* __restrict__ out) {
    int i = (blockIdx.x * 256 + threadIdx.x) * 4;
    float4 v = *(const float4*)(in + i);
    ushort4 o; o.x = f2b(v.x); o.y = f2b(v.y); o.z = f2b(v.z); o.w = f2b(v.w);
    *(ushort4*)(out + i) = o;
}

// ---------------- fp32 -> bf16 cast of the 5 weight matrices ----------------
// wb elems: W1l@0, W1r@16384, W2l@32768, W2r@49152, Wm1@65536 (65536 elems, row-major [256,256])
__global__ __launch_bounds__(256) void cast_w_kernel(
    const float* __restrict__ W1l, const float* __restrict__ W1r,
    const float* __restrict__ W2l, const float* __restrict__ W2r,
    const float* __restrict__ Wm1, unsigned short* __restrict__ wb) {
    int i = (blockIdx.x * 256 + threadIdx.x) * 4;        // 131072 elems / 4
    const float* p;
    if (i < 16384)      p = W1l + i;
    else if (i < 32768) p = W1r + (i - 16384);
    else if (i < 49152) p = W2l + (i - 32768);
    else if (i < 65536) p = W2r + (i - 49152);
    else                p = Wm1 + (i - 65536);
    float4 v = *(const float4*)p;
    ushort4 o; o.x = f2b(v.x); o.y = f2b(v.y); o.z = f2b(v.z); o.w = f2b(v.w);
    *(ushort4*)(wb + i) = o;
}

// ---------------- edge_index canonicalize -> int32 src/dst + degree histogram ----------------
__global__ __launch_bounds__(256) void edge_cvt_hist_kernel(
    const int* __restrict__ ei, int* __restrict__ s32, int* __restrict__ d32,
    int* __restrict__ deg) {
    __shared__ int isI64;
    if (threadIdx.x == 0) {
        int z = 0;
        for (int i = 1; i < 128; i += 2) z |= ei[i];
        isI64 = (z == 0) ? 1 : 0;
    }
    __syncthreads();
    int e = blockIdx.x * 256 + threadIdx.x;
    if (e >= EE) return;
    int s, d;
    if (isI64) {
        const long long* e64 = (const long long*)ei;
        s = (int)e64[e];
        d = (int)e64[EE + e];
    } else {
        s = ei[e];
        d = ei[EE + e];
    }
    s32[e] = s;
    d32[e] = d;
    atomicAdd(&deg[d], 1);
}

// ---------------- device-wide exclusive scan of deg (3 phases) ----------------
// Phase 1: 50 blocks x 1024; per-block LDS inclusive scan; write exclusive-local + block sum.
__global__ __launch_bounds__(1024) void scan_p1_kernel(
    const int* __restrict__ deg, int* __restrict__ exloc, int* __restrict__ bsum) {
    __shared__ int part[1024];
    int t = threadIdx.x, gid = blockIdx.x * 1024 + t;
    int v = (gid < NN) ? deg[gid] : 0;
    part[t] = v;
    __syncthreads();
    for (int off = 1; off < 1024; off <<= 1) {
        int u = (t >= off) ? part[t - off] : 0;
        __syncthreads();
        part[t] += u;
        __syncthreads();
    }
    exloc[gid] = part[t] - v;                  // exclusive within block
    if (t == 1023) bsum[blockIdx.x] = part[t]; // block total
}

// Phase 2: one wave scans the 50 block sums -> exclusive block offsets (in place).
__global__ __launch_bounds__(64) void scan_p2_kernel(int* __restrict__ bsum) {
    int t = threadIdx.x;
    int v = (t < 50) ? bsum[t] : 0;
    int orig = v;
    for (int off = 1; off < 64; off <<= 1) {
        int u = __shfl_up(v, off);
        if (t >= off) v += u;
    }
    if (t < 50) bsum[t] = v - orig;            // exclusive offset
}

// Phase 3: add block offsets, write rowstart + cursor; rowstart[NN] = E.
__global__ __launch_bounds__(1024) void scan_p3_kernel(
    const int* __restrict__ exloc, const int* __restrict__ bsum,
    int* __restrict__ rowstart, int* __restrict__ cursor) {
    int t = threadIdx.x, gid = blockIdx.x * 1024 + t;
    if (gid > NN) return;
    if (gid == NN) { rowstart[NN] = EE; return; }
    int r = exloc[gid] + bsum[blockIdx.x];
    rowstart[gid] = r;
    cursor[gid] = r;
}

__global__ __launch_bounds__(256) void fill_kernel(
    const int* __restrict__ s32, const int* __restrict__ d32,
    int* __restrict__ cursor, int* __restrict__ nbr, int* __restrict__ eid) {
    int e = blockIdx.x * 256 + threadIdx.x;
    if (e < EE) {
        int p = atomicAdd(&cursor[d32[e]], 1);
        nbr[p] = s32[e];
        eid[p] = e;
    }
}

// ---------------- gather aggregation + mean ----------------
// One wave/node; 16 lanes x 16B per neighbor row -> 4 nbrs/load; 4 loads in flight.
__global__ __launch_bounds__(256) void agg_gather_kernel(
    const unsigned short* __restrict__ xin,
    const int* __restrict__ nbr, const int* __restrict__ rowstart,
    unsigned short* __restrict__ aggb) {
    int wave = threadIdx.x >> 6, lane = threadIdx.x & 63;
    int node = blockIdx.x * 4 + wave;
    if (node >= NN) return;
    int part = lane >> 4;                    // 0..3: which neighbor in group of 4
    int col8 = (lane & 15) * 8;              // 8 feats per lane
    int beg = rowstart[node], end = rowstart[node + 1];
    float a[8] = {0,0,0,0,0,0,0,0};
    float b[8] = {0,0,0,0,0,0,0,0};
    int j = beg + part;
    for (; j + 12 < end; j += 16) {          // 4 outstanding 16B loads, 16 nbrs/wave in flight
        int s0 = nbr[j], s1 = nbr[j + 4], s2 = nbr[j + 8], s3 = nbr[j + 12];
        bf16x8 v0 = *(const bf16x8*)(xin + (size_t)s0 * F + col8);
        bf16x8 v1 = *(const bf16x8*)(xin + (size_t)s1 * F + col8);
        bf16x8 v2 = *(const bf16x8*)(xin + (size_t)s2 * F + col8);
        bf16x8 v3 = *(const bf16x8*)(xin + (size_t)s3 * F + col8);
        for (int i = 0; i < 8; i++) a[i] += b2f((unsigned short)v0[i]);
        for (int i = 0; i < 8; i++) b[i] += b2f((unsigned short)v1[i]);
        for (int i = 0; i < 8; i++) a[i] += b2f((unsigned short)v2[i]);
        for (int i = 0; i < 8; i++) b[i] += b2f((unsigned short)v3[i]);
    }
    for (; j < end; j += 4) {
        int s0 = nbr[j];
        bf16x8 v0 = *(const bf16x8*)(xin + (size_t)s0 * F + col8);
        for (int i = 0; i < 8; i++) a[i] += b2f((unsigned short)v0[i]);
    }
    float inv = 1.0f / fmaxf((float)(end - beg), 1.0f);
    unsigned short o[8];
    for (int i = 0; i < 8; i++) {
        float v = a[i] + b[i];
        v += __shfl_xor(v, 16);
        v += __shfl_xor(v, 32);
        o[i] = f2b(v * inv);
    }
    if (part == 0)
        *(bf16x8*)(aggb + (size_t)node * F + col8) = *(bf16x8*)o;
}

// ---------------- fused SAGE combine: out = relu(A1@W1^T + bias + A2@W2^T) ----------------
__global__ __launch_bounds__(256) void node_gemm_kernel(
    const unsigned short* __restrict__ A1, const unsigned short* __restrict__ A2,
    const unsigned short* __restrict__ W1, const unsigned short* __restrict__ W2,
    const float* __restrict__ bias,
    unsigned short* __restrict__ out) {
    int wave = threadIdx.x >> 6, lane = threadIdx.x & 63;
    int c = lane & 15, q = lane >> 4;
    int m0 = (blockIdx.x * 4 + wave) * 16;
    if (m0 >= NN) return;
    f32x4 acc[8];
    for (int nt = 0; nt < 8; nt++) {
        float b = bias[nt * 16 + c];
        acc[nt] = (f32x4){b, b, b, b};
    }
    int mrow = m0 + c; if (mrow > NN - 1) mrow = NN - 1;
    for (int op = 0; op < 2; op++) {
        const unsigned short* ap = (op ? A2 : A1) + (size_t)mrow * F + q * 8;
        const unsigned short* W  = op ? W2 : W1;
        for (int kb = 0; kb < 4; kb++) {
            bf16x8 a = *(const bf16x8*)(ap + kb * 32);
            for (int nt = 0; nt < 8; nt++) {
                bf16x8 b = *(const bf16x8*)(W + (size_t)(nt * 16 + c) * F + kb * 32 + q * 8);
                acc[nt] = __builtin_amdgcn_mfma_f32_16x16x32_bf16(a, b, acc[nt], 0, 0, 0);
            }
        }
    }
    for (int nt = 0; nt < 8; nt++) {
        for (int r = 0; r < 4; r++) {
            int node = m0 + q * 4 + r;
            if (node < NN) {
                float v = fmaxf(acc[nt][r], 0.0f);
                out[(size_t)node * F + nt * 16 + c] = f2b(v);
            }
        }
    }
}

// ---------------- PQ GEMM: PQ[n] = [h2[n]@W1s^T | h2[n]@W1d^T + bm1], bf16 [N,512] ----------
__global__ __launch_bounds__(256) void pq_gemm_kernel(
    const unsigned short* __restrict__ h,      // h2 [N,128] bf16
    const unsigned short* __restrict__ wmb,    // Wm1 bf16 [256,256] row-major
    const float* __restrict__ bm1,             // [256] fp32
    unsigned short* __restrict__ PQ) {         // [N,512] bf16
    int wave = threadIdx.x >> 6, lane = threadIdx.x & 63;
    int c = lane & 15, q = lane >> 4;
    int m0 = (blockIdx.x * 4 + wave) * 16;
    if (m0 >= NN) return;
    int mrow = m0 + c; if (mrow > NN - 1) mrow = NN - 1;
    bf16x8 a[4];
#pragma unroll
    for (int kb = 0; kb < 4; kb++)
        a[kb] = *(const bf16x8*)(h + (size_t)mrow * F + kb * 32 + q * 8);
    for (int half = 0; half < 2; half++) {
        f32x4 acc[16];
#pragma unroll
        for (int nt = 0; nt < 16; nt++) {
            float b = half ? bm1[nt * 16 + c] : 0.0f;
            acc[nt] = (f32x4){b, b, b, b};
        }
#pragma unroll
        for (int kb = 0; kb < 4; kb++) {
#pragma unroll
            for (int nt = 0; nt < 16; nt++) {
                bf16x8 b = *(const bf16x8*)(wmb + (size_t)(nt * 16 + c) * 256 + half * 128 + kb * 32 + q * 8);
                acc[nt] = __builtin_amdgcn_mfma_f32_16x16x32_bf16(a[kb], b, acc[nt], 0, 0, 0);
            }
        }
#pragma unroll
        for (int nt = 0; nt < 16; nt++) {
#pragma unroll
            for (int r = 0; r < 4; r++) {
                int node = m0 + q * 4 + r;
                if (node < NN)
                    PQ[(size_t)node * 512 + half * 256 + nt * 16 + c] = f2b(acc[nt][r]);
            }
        }
    }
}

// ---------------- edge dot: out[eid] = relu(P[src]+Q[dst]).Wm2 + bm2 ----------------
// One wave per dst node via CSR; lane l holds cols l*4..l*4+3; Q loaded once per node.
__global__ __launch_bounds__(256) void edge_dot_kernel(
    const unsigned short* __restrict__ PQ,
    const int* __restrict__ nbr, const int* __restrict__ eid,
    const int* __restrict__ rowstart,
    const float* __restrict__ Wm2, const float* __restrict__ bm2,
    float* __restrict__ out) {
    int wave = threadIdx.x >> 6, lane = threadIdx.x & 63;
    int node = blockIdx.x * 4 + wave;
    if (node >= NN) return;
    float4 w2 = *(const float4*)(Wm2 + lane * 4);
    float b2 = bm2[0];
    ushort4 qv = *(const ushort4*)(PQ + (size_t)node * 512 + 256 + lane * 4);
    float q0 = b2f(qv.x), q1 = b2f(qv.y), q2 = b2f(qv.z), q3 = b2f(qv.w);
    int beg = rowstart[node], end = rowstart[node + 1];
    int j = beg;
    for (; j + 1 < end; j += 2) {
        int s0 = nbr[j], s1 = nbr[j + 1];
        int i0 = eid[j], i1 = eid[j + 1];
        ushort4 p0 = *(const ushort4*)(PQ + (size_t)s0 * 512 + lane * 4);
        ushort4 p1 = *(const ushort4*)(PQ + (size_t)s1 * 512 + lane * 4);
        float t0 = fmaxf(b2f(p0.x) + q0, 0.f) * w2.x + fmaxf(b2f(p0.y) + q1, 0.f) * w2.y
                 + fmaxf(b2f(p0.z) + q2, 0.f) * w2.z + fmaxf(b2f(p0.w) + q3, 0.f) * w2.w;
        float t1 = fmaxf(b2f(p1.x) + q0, 0.f) * w2.x + fmaxf(b2f(p1.y) + q1, 0.f) * w2.y
                 + fmaxf(b2f(p1.z) + q2, 0.f) * w2.z + fmaxf(b2f(p1.w) + q3, 0.f) * w2.w;
#pragma unroll
        for (int o = 1; o < 64; o <<= 1) {
            t0 += __shfl_xor(t0, o);
            t1 += __shfl_xor(t1, o);
        }
        if (lane == 0) { out[i0] = t0 + b2; out[i1] = t1 + b2; }
    }
    if (j < end) {
        int s0 = nbr[j];
        int i0 = eid[j];
        ushort4 p0 = *(const ushort4*)(PQ + (size_t)s0 * 512 + lane * 4);
        float t0 = fmaxf(b2f(p0.x) + q0, 0.f) * w2.x + fmaxf(b2f(p0.y) + q1, 0.f) * w2.y
                 + fmaxf(b2f(p0.z) + q2, 0.f) * w2.z + fmaxf(b2f(p0.w) + q3, 0.f) * w2.w;
#pragma unroll
        for (int o = 1; o < 64; o <<= 1) t0 += __shfl_xor(t0, o);
        if (lane == 0) out[i0] = t0 + b2;
    }
}

extern "C" void kernel_launch(void* const* d_in, const int* in_sizes, int n_in,
                              void* d_out, int out_size, void* d_ws, size_t ws_size,
                              hipStream_t stream) {
    const float* x   = (const float*)d_in[0];
    const int*   ei  = (const int*)d_in[1];
    const float* W1l = (const float*)d_in[2];
    const float* b1l = (const float*)d_in[3];
    const float* W1r = (const float*)d_in[4];
    const float* W2l = (const float*)d_in[5];
    const float* b2l = (const float*)d_in[6];
    const float* W2r = (const float*)d_in[7];
    const float* Wm1 = (const float*)d_in[8];
    const float* bm1 = (const float*)d_in[9];
    const float* Wm2 = (const float*)d_in[10];
    const float* bm2 = (const float*)d_in[11];

    // workspace (bytes), overlays (lifetimes disjoint):
    //   PQ bf16 [50k,512] @0 (51.2M) OVERLAYS {xb@0, h1@12.8M, aggb@25.6M}
    //   wb @51.2M | s32 @51.462M | d32 @54.662M | deg @57.862M | rowstart @58.062M
    //   cursor @58.262M | nbr @58.462M | eid @61.662M | h2 @64.862M | exloc @77.663M | bsum @77.868M
    char* ws = (char*)d_ws;
    unsigned short* PQ       = (unsigned short*)(ws);
    unsigned short* xb       = (unsigned short*)(ws);
    unsigned short* h1       = (unsigned short*)(ws + 12800000);
    unsigned short* aggb     = (unsigned short*)(ws + 25600000);
    unsigned short* wb       = (unsigned short*)(ws + 51200000);
    int*            s32      = (int*)(ws + 51462144);
    int*            d32      = (int*)(ws + 54662144);
    int*            deg      = (int*)(ws + 57862144);
    int*            rowstart = (int*)(ws + 58062208);
    int*            cursor   = (int*)(ws + 58262272);
    int*            nbr      = (int*)(ws + 58462336);
    int*            eid      = (int*)(ws + 61662336);
    unsigned short* h2       = (unsigned short*)(ws + 64862336);
    int*            exloc    = (int*)(ws + 77662336);   // 51200 ints
    int*            bsum     = (int*)(ws + 77867136);   // 64 ints
    float*          outp     = (float*)d_out;

    const unsigned short* w1l_b = wb;
    const unsigned short* w1r_b = wb + 16384;
    const unsigned short* w2l_b = wb + 32768;
    const unsigned short* w2r_b = wb + 49152;
    const unsigned short* wm1_b = wb + 65536;        // plain bf16 [256,256]

    // prep: casts + indices(+hist) + parallel scan + CSR fill
    cast_x_kernel<<<6250, 256, 0, stream>>>(x, xb);
    cast_w_kernel<<<128, 256, 0, stream>>>(W1l, W1r, W2l, W2r, Wm1, wb);
    hipMemsetAsync(deg, 0, 200064, stream);
    edge_cvt_hist_kernel<<<3125, 256, 0, stream>>>(ei, s32, d32, deg);
    scan_p1_kernel<<<50, 1024, 0, stream>>>(deg, exloc, bsum);
    scan_p2_kernel<<<1, 64, 0, stream>>>(bsum);
    scan_p3_kernel<<<50, 1024, 0, stream>>>(exloc, bsum, rowstart, cursor);
    fill_kernel<<<3125, 256, 0, stream>>>(s32, d32, cursor, nbr, eid);

    // layer 1
    agg_gather_kernel<<<12500, 256, 0, stream>>>(xb, nbr, rowstart, aggb);
    node_gemm_kernel<<<782, 256, 0, stream>>>(aggb, xb, w1l_b, w1r_b, b1l, h1);
    // layer 2
    agg_gather_kernel<<<12500, 256, 0, stream>>>(h1, nbr, rowstart, aggb);
    node_gemm_kernel<<<782, 256, 0, stream>>>(aggb, h1, w2l_b, w2r_b, b2l, h2);
    // edge MLP (decomposed)
    pq_gemm_kernel<<<782, 256, 0, stream>>>(h2, wm1_b, bm1, PQ);
    edge_dot_kernel<<<12500, 256, 0, stream>>>(PQ, nbr, eid, rowstart, Wm2, bm2, outp);
}

// Round 10
// 458.009 us; speedup vs baseline: 1.2874x; 1.0540x over previous
//
#include <hip/hip_runtime.h>
#include <hip/hip_bf16.h>

// GraphNet: N=50000 nodes, F=128 feats, H=128, MH=256, E=800000 edges
// Inputs FP32; bf16 workspace copies for MFMA; fp32 MFMA accumulation.
// Edge MLP decomposed: P[n]=h2[n]@W1s^T, Q[n]=h2[n]@W1d^T+bm1 (node-level GEMM),
// then out[e] = relu(P[src]+Q[dst]).Wm2 + bm2 (per-edge dot).
#define NN 50000
#define F 128
#define EE 800000
#define MHD 256

typedef __attribute__((ext_vector_type(8))) short bf16x8;
typedef __attribute__((ext_vector_type(4))) float f32x4;

__device__ __forceinline__ float b2f(unsigned short u) {
    union { unsigned int i; float f; } v; v.i = ((unsigned)u) << 16; return v.f;
}
__device__ __forceinline__ unsigned short f2b(float f) {
    unsigned int x = __float_as_uint(f);
    unsigned int r = x + 0x7fffu + ((x >> 16) & 1u);   // RNE
    return (unsigned short)(r >> 16);
}

// ---------------- fp32 -> bf16 cast of x ----------------
__global__ __launch_bounds__(256) void cast_x_kernel(
    const float* __restrict__ in, unsigned short* __restrict__ out) {
    int i = (blockIdx.x * 256 + threadIdx.x) * 4;
    float4 v = *(const float4*)(in + i);
    ushort4 o; o.x = f2b(v.x); o.y = f2b(v.y); o.z = f2b(v.z); o.w = f2b(v.w);
    *(ushort4*)(out + i) = o;
}

// ---------------- fp32 -> bf16 cast of the 5 weight matrices ----------------
// wb elems: W1l@0, W1r@16384, W2l@32768, W2r@49152, Wm1@65536 (65536 elems, row-major [256,256])
__global__ __launch_bounds__(256) void cast_w_kernel(
    const float* __restrict__ W1l, const float* __restrict__ W1r,
    const float* __restrict__ W2l, const float* __restrict__ W2r,
    const float* __restrict__ Wm1, unsigned short* __restrict__ wb) {
    int i = (blockIdx.x * 256 + threadIdx.x) * 4;        // 131072 elems / 4
    const float* p;
    if (i < 16384)      p = W1l + i;
    else if (i < 32768) p = W1r + (i - 16384);
    else if (i < 49152) p = W2l + (i - 32768);
    else if (i < 65536) p = W2r + (i - 49152);
    else                p = Wm1 + (i - 65536);
    float4 v = *(const float4*)p;
    ushort4 o; o.x = f2b(v.x); o.y = f2b(v.y); o.z = f2b(v.z); o.w = f2b(v.w);
    *(ushort4*)(wb + i) = o;
}

// ---------------- edge_index canonicalize -> int32 src/dst + degree histogram ----------------
__global__ __launch_bounds__(256) void edge_cvt_hist_kernel(
    const int* __restrict__ ei, int* __restrict__ s32, int* __restrict__ d32,
    int* __restrict__ deg) {
    __shared__ int isI64;
    if (threadIdx.x == 0) {
        int z = 0;
        for (int i = 1; i < 128; i += 2) z |= ei[i];
        isI64 = (z == 0) ? 1 : 0;
    }
    __syncthreads();
    int e = blockIdx.x * 256 + threadIdx.x;
    if (e >= EE) return;
    int s, d;
    if (isI64) {
        const long long* e64 = (const long long*)ei;
        s = (int)e64[e];
        d = (int)e64[EE + e];
    } else {
        s = ei[e];
        d = ei[EE + e];
    }
    s32[e] = s;
    d32[e] = d;
    atomicAdd(&deg[d], 1);
}

// ---------------- device-wide exclusive scan of deg (3 phases) ----------------
__global__ __launch_bounds__(1024) void scan_p1_kernel(
    const int* __restrict__ deg, int* __restrict__ exloc, int* __restrict__ bsum) {
    __shared__ int part[1024];
    int t = threadIdx.x, gid = blockIdx.x * 1024 + t;
    int v = (gid < NN) ? deg[gid] : 0;
    part[t] = v;
    __syncthreads();
    for (int off = 1; off < 1024; off <<= 1) {
        int u = (t >= off) ? part[t - off] : 0;
        __syncthreads();
        part[t] += u;
        __syncthreads();
    }
    exloc[gid] = part[t] - v;
    if (t == 1023) bsum[blockIdx.x] = part[t];
}

__global__ __launch_bounds__(64) void scan_p2_kernel(int* __restrict__ bsum) {
    int t = threadIdx.x;
    int v = (t < 50) ? bsum[t] : 0;
    int orig = v;
    for (int off = 1; off < 64; off <<= 1) {
        int u = __shfl_up(v, off);
        if (t >= off) v += u;
    }
    if (t < 50) bsum[t] = v - orig;
}

__global__ __launch_bounds__(1024) void scan_p3_kernel(
    const int* __restrict__ exloc, const int* __restrict__ bsum,
    int* __restrict__ rowstart, int* __restrict__ cursor) {
    int t = threadIdx.x, gid = blockIdx.x * 1024 + t;
    if (gid > NN) return;
    if (gid == NN) { rowstart[NN] = EE; return; }
    int r = exloc[gid] + bsum[blockIdx.x];
    rowstart[gid] = r;
    cursor[gid] = r;
}

__global__ __launch_bounds__(256) void fill_kernel(
    const int* __restrict__ s32, const int* __restrict__ d32,
    int* __restrict__ cursor, int* __restrict__ nbr, int* __restrict__ eid) {
    int e = blockIdx.x * 256 + threadIdx.x;
    if (e < EE) {
        int p = atomicAdd(&cursor[d32[e]], 1);
        nbr[p] = s32[e];
        eid[p] = e;
    }
}

// ---------------- gather aggregation + mean ----------------
__global__ __launch_bounds__(256) void agg_gather_kernel(
    const unsigned short* __restrict__ xin,
    const int* __restrict__ nbr, const int* __restrict__ rowstart,
    unsigned short* __restrict__ aggb) {
    int wave = threadIdx.x >> 6, lane = threadIdx.x & 63;
    int node = blockIdx.x * 4 + wave;
    if (node >= NN) return;
    int part = lane >> 4;
    int col8 = (lane & 15) * 8;
    int beg = rowstart[node], end = rowstart[node + 1];
    float a[8] = {0,0,0,0,0,0,0,0};
    float b[8] = {0,0,0,0,0,0,0,0};
    int j = beg + part;
    for (; j + 12 < end; j += 16) {
        int s0 = nbr[j], s1 = nbr[j + 4], s2 = nbr[j + 8], s3 = nbr[j + 12];
        bf16x8 v0 = *(const bf16x8*)(xin + (size_t)s0 * F + col8);
        bf16x8 v1 = *(const bf16x8*)(xin + (size_t)s1 * F + col8);
        bf16x8 v2 = *(const bf16x8*)(xin + (size_t)s2 * F + col8);
        bf16x8 v3 = *(const bf16x8*)(xin + (size_t)s3 * F + col8);
        for (int i = 0; i < 8; i++) a[i] += b2f((unsigned short)v0[i]);
        for (int i = 0; i < 8; i++) b[i] += b2f((unsigned short)v1[i]);
        for (int i = 0; i < 8; i++) a[i] += b2f((unsigned short)v2[i]);
        for (int i = 0; i < 8; i++) b[i] += b2f((unsigned short)v3[i]);
    }
    for (; j < end; j += 4) {
        int s0 = nbr[j];
        bf16x8 v0 = *(const bf16x8*)(xin + (size_t)s0 * F + col8);
        for (int i = 0; i < 8; i++) a[i] += b2f((unsigned short)v0[i]);
    }
    float inv = 1.0f / fmaxf((float)(end - beg), 1.0f);
    unsigned short o[8];
    for (int i = 0; i < 8; i++) {
        float v = a[i] + b[i];
        v += __shfl_xor(v, 16);
        v += __shfl_xor(v, 32);
        o[i] = f2b(v * inv);
    }
    if (part == 0)
        *(bf16x8*)(aggb + (size_t)node * F + col8) = *(bf16x8*)o;
}

// ---------------- fused SAGE combine: out = relu(A1@W1^T + bias + A2@W2^T) ----------------
__global__ __launch_bounds__(256) void node_gemm_kernel(
    const unsigned short* __restrict__ A1, const unsigned short* __restrict__ A2,
    const unsigned short* __restrict__ W1, const unsigned short* __restrict__ W2,
    const float* __restrict__ bias,
    unsigned short* __restrict__ out) {
    int wave = threadIdx.x >> 6, lane = threadIdx.x & 63;
    int c = lane & 15, q = lane >> 4;
    int m0 = (blockIdx.x * 4 + wave) * 16;
    if (m0 >= NN) return;
    f32x4 acc[8];
    for (int nt = 0; nt < 8; nt++) {
        float b = bias[nt * 16 + c];
        acc[nt] = (f32x4){b, b, b, b};
    }
    int mrow = m0 + c; if (mrow > NN - 1) mrow = NN - 1;
    for (int op = 0; op < 2; op++) {
        const unsigned short* ap = (op ? A2 : A1) + (size_t)mrow * F + q * 8;
        const unsigned short* W  = op ? W2 : W1;
        for (int kb = 0; kb < 4; kb++) {
            bf16x8 a = *(const bf16x8*)(ap + kb * 32);
            for (int nt = 0; nt < 8; nt++) {
                bf16x8 b = *(const bf16x8*)(W + (size_t)(nt * 16 + c) * F + kb * 32 + q * 8);
                acc[nt] = __builtin_amdgcn_mfma_f32_16x16x32_bf16(a, b, acc[nt], 0, 0, 0);
            }
        }
    }
    for (int nt = 0; nt < 8; nt++) {
        for (int r = 0; r < 4; r++) {
            int node = m0 + q * 4 + r;
            if (node < NN) {
                float v = fmaxf(acc[nt][r], 0.0f);
                out[(size_t)node * F + nt * 16 + c] = f2b(v);
            }
        }
    }
}

// ---------------- PQ GEMM: PQ[n] = [h2[n]@W1s^T | h2[n]@W1d^T + bm1], bf16 [N,512] ----------
__global__ __launch_bounds__(256) void pq_gemm_kernel(
    const unsigned short* __restrict__ h,
    const unsigned short* __restrict__ wmb,
    const float* __restrict__ bm1,
    unsigned short* __restrict__ PQ) {
    int wave = threadIdx.x >> 6, lane = threadIdx.x & 63;
    int c = lane & 15, q = lane >> 4;
    int m0 = (blockIdx.x * 4 + wave) * 16;
    if (m0 >= NN) return;
    int mrow = m0 + c; if (mrow > NN - 1) mrow = NN - 1;
    bf16x8 a[4];
#pragma unroll
    for (int kb = 0; kb < 4; kb++)
        a[kb] = *(const bf16x8*)(h + (size_t)mrow * F + kb * 32 + q * 8);
    for (int half = 0; half < 2; half++) {
        f32x4 acc[16];
#pragma unroll
        for (int nt = 0; nt < 16; nt++) {
            float b = half ? bm1[nt * 16 + c] : 0.0f;
            acc[nt] = (f32x4){b, b, b, b};
        }
#pragma unroll
        for (int kb = 0; kb < 4; kb++) {
#pragma unroll
            for (int nt = 0; nt < 16; nt++) {
                bf16x8 b = *(const bf16x8*)(wmb + (size_t)(nt * 16 + c) * 256 + half * 128 + kb * 32 + q * 8);
                acc[nt] = __builtin_amdgcn_mfma_f32_16x16x32_bf16(a[kb], b, acc[nt], 0, 0, 0);
            }
        }
#pragma unroll
        for (int nt = 0; nt < 16; nt++) {
#pragma unroll
            for (int r = 0; r < 4; r++) {
                int node = m0 + q * 4 + r;
                if (node < NN)
                    PQ[(size_t)node * 512 + half * 256 + nt * 16 + c] = f2b(acc[nt][r]);
            }
        }
    }
}

// ---------------- edge dot: out[eid] = relu(P[src]+Q[dst]).Wm2 + bm2 ----------------
// One wave per dst node; 16 lanes per edge (lane l16 owns cols l16*16..+15), 4 edges/iter.
// Reduction: 4 shfl_xor (masks 1,2,4,8) reduce all 4 groups simultaneously -> 1 shfl/edge
// (was 6/edge with the 64-wide chain). Q and Wm2 held as 16 fp32 regs/lane, loaded per node.
__global__ __launch_bounds__(256) void edge_dot_kernel(
    const unsigned short* __restrict__ PQ,
    const int* __restrict__ nbr, const int* __restrict__ eid,
    const int* __restrict__ rowstart,
    const float* __restrict__ Wm2, const float* __restrict__ bm2,
    float* __restrict__ out) {
    int wave = threadIdx.x >> 6, lane = threadIdx.x & 63;
    int node = blockIdx.x * 4 + wave;
    if (node >= NN) return;
    int g = lane >> 4, l16 = lane & 15;
    int col = l16 * 16;                      // 16 cols per lane
    float w2f[16], qf[16];
    {
        float4 wa = *(const float4*)(Wm2 + col);
        float4 wbv = *(const float4*)(Wm2 + col + 4);
        float4 wc = *(const float4*)(Wm2 + col + 8);
        float4 wd = *(const float4*)(Wm2 + col + 12);
        w2f[0]=wa.x; w2f[1]=wa.y; w2f[2]=wa.z; w2f[3]=wa.w;
        w2f[4]=wbv.x; w2f[5]=wbv.y; w2f[6]=wbv.z; w2f[7]=wbv.w;
        w2f[8]=wc.x; w2f[9]=wc.y; w2f[10]=wc.z; w2f[11]=wc.w;
        w2f[12]=wd.x; w2f[13]=wd.y; w2f[14]=wd.z; w2f[15]=wd.w;
        bf16x8 q0 = *(const bf16x8*)(PQ + (size_t)node * 512 + 256 + col);
        bf16x8 q1 = *(const bf16x8*)(PQ + (size_t)node * 512 + 256 + col + 8);
#pragma unroll
        for (int i = 0; i < 8; i++) { qf[i] = b2f((unsigned short)q0[i]); qf[8 + i] = b2f((unsigned short)q1[i]); }
    }
    float b2 = bm2[0];
    int beg = rowstart[node], end = rowstart[node + 1];
    for (int j = beg + g; j < end; j += 4) {
        int s = nbr[j];
        int id = eid[j];
        const unsigned short* prow = PQ + (size_t)s * 512 + col;
        bf16x8 p0 = *(const bf16x8*)(prow);
        bf16x8 p1 = *(const bf16x8*)(prow + 8);
        float t = 0.f;
#pragma unroll
        for (int i = 0; i < 8; i++)
            t += fmaxf(b2f((unsigned short)p0[i]) + qf[i], 0.f) * w2f[i];
#pragma unroll
        for (int i = 0; i < 8; i++)
            t += fmaxf(b2f((unsigned short)p1[i]) + qf[8 + i], 0.f) * w2f[8 + i];
        t += __shfl_xor(t, 1);
        t += __shfl_xor(t, 2);
        t += __shfl_xor(t, 4);
        t += __shfl_xor(t, 8);
        if (l16 == 0) out[id] = t + b2;
    }
}

extern "C" void kernel_launch(void* const* d_in, const int* in_sizes, int n_in,
                              void* d_out, int out_size, void* d_ws, size_t ws_size,
                              hipStream_t stream) {
    const float* x   = (const float*)d_in[0];
    const int*   ei  = (const int*)d_in[1];
    const float* W1l = (const float*)d_in[2];
    const float* b1l = (const float*)d_in[3];
    const float* W1r = (const float*)d_in[4];
    const float* W2l = (const float*)d_in[5];
    const float* b2l = (const float*)d_in[6];
    const float* W2r = (const float*)d_in[7];
    const float* Wm1 = (const float*)d_in[8];
    const float* bm1 = (const float*)d_in[9];
    const float* Wm2 = (const float*)d_in[10];
    const float* bm2 = (const float*)d_in[11];

    char* ws = (char*)d_ws;
    unsigned short* PQ       = (unsigned short*)(ws);
    unsigned short* xb       = (unsigned short*)(ws);
    unsigned short* h1       = (unsigned short*)(ws + 12800000);
    unsigned short* aggb     = (unsigned short*)(ws + 25600000);
    unsigned short* wb       = (unsigned short*)(ws + 51200000);
    int*            s32      = (int*)(ws + 51462144);
    int*            d32      = (int*)(ws + 54662144);
    int*            deg      = (int*)(ws + 57862144);
    int*            rowstart = (int*)(ws + 58062208);
    int*            cursor   = (int*)(ws + 58262272);
    int*            nbr      = (int*)(ws + 58462336);
    int*            eid      = (int*)(ws + 61662336);
    unsigned short* h2       = (unsigned short*)(ws + 64862336);
    int*            exloc    = (int*)(ws + 77662336);
    int*            bsum     = (int*)(ws + 77867136);
    float*          outp     = (float*)d_out;

    const unsigned short* w1l_b = wb;
    const unsigned short* w1r_b = wb + 16384;
    const unsigned short* w2l_b = wb + 32768;
    const unsigned short* w2r_b = wb + 49152;
    const unsigned short* wm1_b = wb + 65536;

    // prep: casts + indices(+hist) + parallel scan + CSR fill
    cast_x_kernel<<<6250, 256, 0, stream>>>(x, xb);
    cast_w_kernel<<<128, 256, 0, stream>>>(W1l, W1r, W2l, W2r, Wm1, wb);
    hipMemsetAsync(deg, 0, 200064, stream);
    edge_cvt_hist_kernel<<<3125, 256, 0, stream>>>(ei, s32, d32, deg);
    scan_p1_kernel<<<50, 1024, 0, stream>>>(deg, exloc, bsum);
    scan_p2_kernel<<<1, 64, 0, stream>>>(bsum);
    scan_p3_kernel<<<50, 1024, 0, stream>>>(exloc, bsum, rowstart, cursor);
    fill_kernel<<<3125, 256, 0, stream>>>(s32, d32, cursor, nbr, eid);

    // layer 1
    agg_gather_kernel<<<12500, 256, 0, stream>>>(xb, nbr, rowstart, aggb);
    node_gemm_kernel<<<782, 256, 0, stream>>>(aggb, xb, w1l_b, w1r_b, b1l, h1);
    // layer 2
    agg_gather_kernel<<<12500, 256, 0, stream>>>(h1, nbr, rowstart, aggb);
    node_gemm_kernel<<<782, 256, 0, stream>>>(aggb, h1, w2l_b, w2r_b, b2l, h2);
    // edge MLP (decomposed)
    pq_gemm_kernel<<<782, 256, 0, stream>>>(h2, wm1_b, bm1, PQ);
    edge_dot_kernel<<<12500, 256, 0, stream>>>(PQ, nbr, eid, rowstart, Wm2, bm2, outp);
}

// Round 11
// 443.253 us; speedup vs baseline: 1.3302x; 1.0333x over previous
//
#include <hip/hip_runtime.h>
#include <hip/hip_bf16.h>

// GraphNet: N=50000 nodes, F=128 feats, H=128, MH=256, E=800000 edges
// Inputs FP32; bf16 workspace copies for MFMA; fp32 MFMA accumulation.
// Edge MLP decomposed: P[n]=h2[n]@W1s^T, Q[n]=h2[n]@W1d^T+bm1 (node GEMM, PERMUTED col
// layout col'=c*16+nt for vectorized stores), then out[e]=relu(P[src]+Q[dst]).Wm2p + bm2.
#define NN 50000
#define F 128
#define EE 800000
#define MHD 256

typedef __attribute__((ext_vector_type(8))) short bf16x8;
typedef __attribute__((ext_vector_type(4))) float f32x4;

__device__ __forceinline__ float b2f(unsigned short u) {
    union { unsigned int i; float f; } v; v.i = ((unsigned)u) << 16; return v.f;
}
__device__ __forceinline__ unsigned short f2b(float f) {
    unsigned int x = __float_as_uint(f);
    unsigned int r = x + 0x7fffu + ((x >> 16) & 1u);   // RNE
    return (unsigned short)(r >> 16);
}

// ---------------- fp32 -> bf16 cast of x ----------------
__global__ __launch_bounds__(256) void cast_x_kernel(
    const float* __restrict__ in, unsigned short* __restrict__ out) {
    int i = (blockIdx.x * 256 + threadIdx.x) * 4;
    float4 v = *(const float4*)(in + i);
    ushort4 o; o.x = f2b(v.x); o.y = f2b(v.y); o.z = f2b(v.z); o.w = f2b(v.w);
    *(ushort4*)(out + i) = o;
}

// ---------------- fp32 -> bf16 cast of the 5 weight matrices ----------------
// wb elems: W1l@0, W1r@16384, W2l@32768, W2r@49152, Wm1@65536 (65536 elems, row-major [256,256])
__global__ __launch_bounds__(256) void cast_w_kernel(
    const float* __restrict__ W1l, const float* __restrict__ W1r,
    const float* __restrict__ W2l, const float* __restrict__ W2r,
    const float* __restrict__ Wm1, unsigned short* __restrict__ wb) {
    int i = (blockIdx.x * 256 + threadIdx.x) * 4;        // 131072 elems / 4
    const float* p;
    if (i < 16384)      p = W1l + i;
    else if (i < 32768) p = W1r + (i - 16384);
    else if (i < 49152) p = W2l + (i - 32768);
    else if (i < 65536) p = W2r + (i - 49152);
    else                p = Wm1 + (i - 65536);
    float4 v = *(const float4*)p;
    ushort4 o; o.x = f2b(v.x); o.y = f2b(v.y); o.z = f2b(v.z); o.w = f2b(v.w);
    *(ushort4*)(wb + i) = o;
}

// ---------------- edge_index canonicalize -> int32 src/dst + degree histogram ----------------
__global__ __launch_bounds__(256) void edge_cvt_hist_kernel(
    const int* __restrict__ ei, int* __restrict__ s32, int* __restrict__ d32,
    int* __restrict__ deg) {
    __shared__ int isI64;
    if (threadIdx.x == 0) {
        int z = 0;
        for (int i = 1; i < 128; i += 2) z |= ei[i];
        isI64 = (z == 0) ? 1 : 0;
    }
    __syncthreads();
    int e = blockIdx.x * 256 + threadIdx.x;
    if (e >= EE) return;
    int s, d;
    if (isI64) {
        const long long* e64 = (const long long*)ei;
        s = (int)e64[e];
        d = (int)e64[EE + e];
    } else {
        s = ei[e];
        d = ei[EE + e];
    }
    s32[e] = s;
    d32[e] = d;
    atomicAdd(&deg[d], 1);
}

// ---------------- device-wide exclusive scan of deg (3 phases) ----------------
__global__ __launch_bounds__(1024) void scan_p1_kernel(
    const int* __restrict__ deg, int* __restrict__ exloc, int* __restrict__ bsum) {
    __shared__ int part[1024];
    int t = threadIdx.x, gid = blockIdx.x * 1024 + t;
    int v = (gid < NN) ? deg[gid] : 0;
    part[t] = v;
    __syncthreads();
    for (int off = 1; off < 1024; off <<= 1) {
        int u = (t >= off) ? part[t - off] : 0;
        __syncthreads();
        part[t] += u;
        __syncthreads();
    }
    exloc[gid] = part[t] - v;
    if (t == 1023) bsum[blockIdx.x] = part[t];
}

__global__ __launch_bounds__(64) void scan_p2_kernel(int* __restrict__ bsum) {
    int t = threadIdx.x;
    int v = (t < 50) ? bsum[t] : 0;
    int orig = v;
    for (int off = 1; off < 64; off <<= 1) {
        int u = __shfl_up(v, off);
        if (t >= off) v += u;
    }
    if (t < 50) bsum[t] = v - orig;
}

__global__ __launch_bounds__(1024) void scan_p3_kernel(
    const int* __restrict__ exloc, const int* __restrict__ bsum,
    int* __restrict__ rowstart, int* __restrict__ cursor) {
    int t = threadIdx.x, gid = blockIdx.x * 1024 + t;
    if (gid > NN) return;
    if (gid == NN) { rowstart[NN] = EE; return; }
    int r = exloc[gid] + bsum[blockIdx.x];
    rowstart[gid] = r;
    cursor[gid] = r;
}

__global__ __launch_bounds__(256) void fill_kernel(
    const int* __restrict__ s32, const int* __restrict__ d32,
    int* __restrict__ cursor, int* __restrict__ nbr, int* __restrict__ eid) {
    int e = blockIdx.x * 256 + threadIdx.x;
    if (e < EE) {
        int p = atomicAdd(&cursor[d32[e]], 1);
        nbr[p] = s32[e];
        eid[p] = e;
    }
}

// ---------------- gather aggregation + mean ----------------
__global__ __launch_bounds__(256) void agg_gather_kernel(
    const unsigned short* __restrict__ xin,
    const int* __restrict__ nbr, const int* __restrict__ rowstart,
    unsigned short* __restrict__ aggb) {
    int wave = threadIdx.x >> 6, lane = threadIdx.x & 63;
    int node = blockIdx.x * 4 + wave;
    if (node >= NN) return;
    int part = lane >> 4;
    int col8 = (lane & 15) * 8;
    int beg = rowstart[node], end = rowstart[node + 1];
    float a[8] = {0,0,0,0,0,0,0,0};
    float b[8] = {0,0,0,0,0,0,0,0};
    int j = beg + part;
    for (; j + 12 < end; j += 16) {
        int s0 = nbr[j], s1 = nbr[j + 4], s2 = nbr[j + 8], s3 = nbr[j + 12];
        bf16x8 v0 = *(const bf16x8*)(xin + (size_t)s0 * F + col8);
        bf16x8 v1 = *(const bf16x8*)(xin + (size_t)s1 * F + col8);
        bf16x8 v2 = *(const bf16x8*)(xin + (size_t)s2 * F + col8);
        bf16x8 v3 = *(const bf16x8*)(xin + (size_t)s3 * F + col8);
        for (int i = 0; i < 8; i++) a[i] += b2f((unsigned short)v0[i]);
        for (int i = 0; i < 8; i++) b[i] += b2f((unsigned short)v1[i]);
        for (int i = 0; i < 8; i++) a[i] += b2f((unsigned short)v2[i]);
        for (int i = 0; i < 8; i++) b[i] += b2f((unsigned short)v3[i]);
    }
    for (; j < end; j += 4) {
        int s0 = nbr[j];
        bf16x8 v0 = *(const bf16x8*)(xin + (size_t)s0 * F + col8);
        for (int i = 0; i < 8; i++) a[i] += b2f((unsigned short)v0[i]);
    }
    float inv = 1.0f / fmaxf((float)(end - beg), 1.0f);
    unsigned short o[8];
    for (int i = 0; i < 8; i++) {
        float v = a[i] + b[i];
        v += __shfl_xor(v, 16);
        v += __shfl_xor(v, 32);
        o[i] = f2b(v * inv);
    }
    if (part == 0)
        *(bf16x8*)(aggb + (size_t)node * F + col8) = *(bf16x8*)o;
}

// ---------------- fused SAGE combine: out = relu(A1@W1^T + bias + A2@W2^T) ----------------
__global__ __launch_bounds__(256) void node_gemm_kernel(
    const unsigned short* __restrict__ A1, const unsigned short* __restrict__ A2,
    const unsigned short* __restrict__ W1, const unsigned short* __restrict__ W2,
    const float* __restrict__ bias,
    unsigned short* __restrict__ out) {
    int wave = threadIdx.x >> 6, lane = threadIdx.x & 63;
    int c = lane & 15, q = lane >> 4;
    int m0 = (blockIdx.x * 4 + wave) * 16;
    if (m0 >= NN) return;
    f32x4 acc[8];
    for (int nt = 0; nt < 8; nt++) {
        float b = bias[nt * 16 + c];
        acc[nt] = (f32x4){b, b, b, b};
    }
    int mrow = m0 + c; if (mrow > NN - 1) mrow = NN - 1;
    for (int op = 0; op < 2; op++) {
        const unsigned short* ap = (op ? A2 : A1) + (size_t)mrow * F + q * 8;
        const unsigned short* W  = op ? W2 : W1;
        for (int kb = 0; kb < 4; kb++) {
            bf16x8 a = *(const bf16x8*)(ap + kb * 32);
            for (int nt = 0; nt < 8; nt++) {
                bf16x8 b = *(const bf16x8*)(W + (size_t)(nt * 16 + c) * F + kb * 32 + q * 8);
                acc[nt] = __builtin_amdgcn_mfma_f32_16x16x32_bf16(a, b, acc[nt], 0, 0, 0);
            }
        }
    }
    for (int nt = 0; nt < 8; nt++) {
        for (int r = 0; r < 4; r++) {
            int node = m0 + q * 4 + r;
            if (node < NN) {
                float v = fmaxf(acc[nt][r], 0.0f);
                out[(size_t)node * F + nt * 16 + c] = f2b(v);
            }
        }
    }
}

// ---------------- PQ GEMM (wave-split N, permuted cols): PQ[n] bf16 [N,512] ----------------
// Wave w of block: half = w>>1, ntBase = (w&1)*8. Each wave: 16 nodes x 128 cols.
// Permuted col within half: col' = c*16 + (ntBase+nt)  -> per-(node,r) 8 accs contiguous,
// ONE 16B store (was 128 x 2B scalar stores). edge_dot gathers Wm2 with inverse perm.
__global__ __launch_bounds__(256) void pq_gemm_kernel(
    const unsigned short* __restrict__ h,
    const unsigned short* __restrict__ wmb,
    const float* __restrict__ bm1,
    unsigned short* __restrict__ PQ) {
    int wave = threadIdx.x >> 6, lane = threadIdx.x & 63;
    int c = lane & 15, q = lane >> 4;
    int half = wave >> 1, ntBase = (wave & 1) * 8;
    int m0 = blockIdx.x * 16;
    int mrow = m0 + c; if (mrow > NN - 1) mrow = NN - 1;
    bf16x8 a[4];
#pragma unroll
    for (int kb = 0; kb < 4; kb++)
        a[kb] = *(const bf16x8*)(h + (size_t)mrow * F + kb * 32 + q * 8);
    f32x4 acc[8];
#pragma unroll
    for (int nt = 0; nt < 8; nt++) {
        float b = half ? bm1[(ntBase + nt) * 16 + c] : 0.0f;
        acc[nt] = (f32x4){b, b, b, b};
    }
#pragma unroll
    for (int kb = 0; kb < 4; kb++) {
#pragma unroll
        for (int nt = 0; nt < 8; nt++) {
            bf16x8 b = *(const bf16x8*)(wmb + (size_t)((ntBase + nt) * 16 + c) * 256 + half * 128 + kb * 32 + q * 8);
            acc[nt] = __builtin_amdgcn_mfma_f32_16x16x32_bf16(a[kb], b, acc[nt], 0, 0, 0);
        }
    }
#pragma unroll
    for (int r = 0; r < 4; r++) {
        int node = m0 + q * 4 + r;
        if (node < NN) {
            unsigned short o[8];
#pragma unroll
            for (int nt = 0; nt < 8; nt++) o[nt] = f2b(acc[nt][r]);
            *(bf16x8*)(PQ + (size_t)node * 512 + half * 256 + c * 16 + ntBase) = *(bf16x8*)o;
        }
    }
}

// ---------------- edge dot: out[eid] = relu(P[src]+Q[dst]).Wm2p + bm2 ----------------
// One wave per dst node; 16 lanes per edge, 4 edges/iter. PQ cols are permuted
// (col' = c*16+nt), so Wm2 is gathered with the inverse perm: w2f[i] = Wm2[i*16+l16].
__global__ __launch_bounds__(256) void edge_dot_kernel(
    const unsigned short* __restrict__ PQ,
    const int* __restrict__ nbr, const int* __restrict__ eid,
    const int* __restrict__ rowstart,
    const float* __restrict__ Wm2, const float* __restrict__ bm2,
    float* __restrict__ out) {
    int wave = threadIdx.x >> 6, lane = threadIdx.x & 63;
    int node = blockIdx.x * 4 + wave;
    if (node >= NN) return;
    int g = lane >> 4, l16 = lane & 15;
    int col = l16 * 16;                      // 16 permuted cols per lane
    float w2f[16], qf[16];
#pragma unroll
    for (int i = 0; i < 16; i++) w2f[i] = Wm2[i * 16 + l16];   // inverse perm gather
    {
        bf16x8 q0 = *(const bf16x8*)(PQ + (size_t)node * 512 + 256 + col);
        bf16x8 q1 = *(const bf16x8*)(PQ + (size_t)node * 512 + 256 + col + 8);
#pragma unroll
        for (int i = 0; i < 8; i++) { qf[i] = b2f((unsigned short)q0[i]); qf[8 + i] = b2f((unsigned short)q1[i]); }
    }
    float b2 = bm2[0];
    int beg = rowstart[node], end = rowstart[node + 1];
    for (int j = beg + g; j < end; j += 4) {
        int s = nbr[j];
        int id = eid[j];
        const unsigned short* prow = PQ + (size_t)s * 512 + col;
        bf16x8 p0 = *(const bf16x8*)(prow);
        bf16x8 p1 = *(const bf16x8*)(prow + 8);
        float t = 0.f;
#pragma unroll
        for (int i = 0; i < 8; i++)
            t += fmaxf(b2f((unsigned short)p0[i]) + qf[i], 0.f) * w2f[i];
#pragma unroll
        for (int i = 0; i < 8; i++)
            t += fmaxf(b2f((unsigned short)p1[i]) + qf[8 + i], 0.f) * w2f[8 + i];
        t += __shfl_xor(t, 1);
        t += __shfl_xor(t, 2);
        t += __shfl_xor(t, 4);
        t += __shfl_xor(t, 8);
        if (l16 == 0) out[id] = t + b2;
    }
}

extern "C" void kernel_launch(void* const* d_in, const int* in_sizes, int n_in,
                              void* d_out, int out_size, void* d_ws, size_t ws_size,
                              hipStream_t stream) {
    const float* x   = (const float*)d_in[0];
    const int*   ei  = (const int*)d_in[1];
    const float* W1l = (const float*)d_in[2];
    const float* b1l = (const float*)d_in[3];
    const float* W1r = (const float*)d_in[4];
    const float* W2l = (const float*)d_in[5];
    const float* b2l = (const float*)d_in[6];
    const float* W2r = (const float*)d_in[7];
    const float* Wm1 = (const float*)d_in[8];
    const float* bm1 = (const float*)d_in[9];
    const float* Wm2 = (const float*)d_in[10];
    const float* bm2 = (const float*)d_in[11];

    char* ws = (char*)d_ws;
    unsigned short* PQ       = (unsigned short*)(ws);
    unsigned short* xb       = (unsigned short*)(ws);
    unsigned short* h1       = (unsigned short*)(ws + 12800000);
    unsigned short* aggb     = (unsigned short*)(ws + 25600000);
    unsigned short* wb       = (unsigned short*)(ws + 51200000);
    int*            s32      = (int*)(ws + 51462144);
    int*            d32      = (int*)(ws + 54662144);
    int*            deg      = (int*)(ws + 57862144);
    int*            rowstart = (int*)(ws + 58062208);
    int*            cursor   = (int*)(ws + 58262272);
    int*            nbr      = (int*)(ws + 58462336);
    int*            eid      = (int*)(ws + 61662336);
    unsigned short* h2       = (unsigned short*)(ws + 64862336);
    int*            exloc    = (int*)(ws + 77662336);
    int*            bsum     = (int*)(ws + 77867136);
    float*          outp     = (float*)d_out;

    const unsigned short* w1l_b = wb;
    const unsigned short* w1r_b = wb + 16384;
    const unsigned short* w2l_b = wb + 32768;
    const unsigned short* w2r_b = wb + 49152;
    const unsigned short* wm1_b = wb + 65536;

    // prep: casts + indices(+hist) + parallel scan + CSR fill
    cast_x_kernel<<<6250, 256, 0, stream>>>(x, xb);
    cast_w_kernel<<<128, 256, 0, stream>>>(W1l, W1r, W2l, W2r, Wm1, wb);
    hipMemsetAsync(deg, 0, 200064, stream);
    edge_cvt_hist_kernel<<<3125, 256, 0, stream>>>(ei, s32, d32, deg);
    scan_p1_kernel<<<50, 1024, 0, stream>>>(deg, exloc, bsum);
    scan_p2_kernel<<<1, 64, 0, stream>>>(bsum);
    scan_p3_kernel<<<50, 1024, 0, stream>>>(exloc, bsum, rowstart, cursor);
    fill_kernel<<<3125, 256, 0, stream>>>(s32, d32, cursor, nbr, eid);

    // layer 1
    agg_gather_kernel<<<12500, 256, 0, stream>>>(xb, nbr, rowstart, aggb);
    node_gemm_kernel<<<782, 256, 0, stream>>>(aggb, xb, w1l_b, w1r_b, b1l, h1);
    // layer 2
    agg_gather_kernel<<<12500, 256, 0, stream>>>(h1, nbr, rowstart, aggb);
    node_gemm_kernel<<<782, 256, 0, stream>>>(aggb, h1, w2l_b, w2r_b, b2l, h2);
    // edge MLP (decomposed)
    pq_gemm_kernel<<<3125, 256, 0, stream>>>(h2, wm1_b, bm1, PQ);
    edge_dot_kernel<<<12500, 256, 0, stream>>>(PQ, nbr, eid, rowstart, Wm2, bm2, outp);
}